// Round 7
// baseline (481.029 us; speedup 1.0000x reference)
//
#include <hip/hip_runtime.h>
#include <hip/hip_bf16.h>

#define BB 4
#define HH 16
#define LL 2048
#define DD 64
#define EE 1024
#define MM (BB*LL)   // 8192 rows
#define SCL 0.125f
#define L2E 1.44269504f

using bf16   = __hip_bfloat16;
using bf16x8 = __attribute__((ext_vector_type(8))) __bf16;
using s16x4  = __attribute__((ext_vector_type(4))) short;
using f32x4  = __attribute__((ext_vector_type(4))) float;
using u32x4  = __attribute__((ext_vector_type(4))) unsigned int;
typedef unsigned int u32;

// ---- dtype-polymorphic helpers (verified R2/R4) ----
__device__ __forceinline__ bf16x8 ld8(const bf16* p){ return *(const bf16x8*)p; }
__device__ __forceinline__ bf16x8 ld8(const float* p){
  u32x4 a = *(const u32x4*)p;
  u32x4 b = *(const u32x4*)(p + 4);
  union { bf16x8 v; unsigned short s[8]; } r;
#pragma unroll
  for (int i = 0; i < 4; i++) r.s[i]     = (unsigned short)((a[i] + 0x7FFFu + ((a[i] >> 16) & 1u)) >> 16);
#pragma unroll
  for (int i = 0; i < 4; i++) r.s[i + 4] = (unsigned short)((b[i] + 0x7FFFu + ((b[i] >> 16) & 1u)) >> 16);
  return r.v;
}
__device__ __forceinline__ float ldf(const bf16* p){ return __bfloat162float(*p); }
__device__ __forceinline__ float ldf(const float* p){ return *p; }
__device__ __forceinline__ bf16 to_b(bf16 v){ return v; }
__device__ __forceinline__ bf16 to_b(float v){ return __float2bfloat16(v); }

// async global->LDS, 16B/lane; LDS dest = wave-uniform base + lane*16 (m97/m104)
__device__ __forceinline__ void async16(const bf16* g, bf16* l) {
  __builtin_amdgcn_global_load_lds((const __attribute__((address_space(1))) u32*)g,
                                   (__attribute__((address_space(3))) u32*)l, 16, 0, 0);
}

// ---- dtype detect (verified R2/R4) ----
__global__ __launch_bounds__(256) void detect_dtype(const unsigned int* __restrict__ w,
                                                    int* __restrict__ flag) {
  __shared__ int cnt[256];
  int tid = threadIdx.x;
  int c = 0;
  for (int i = 0; i < 16; i++) {
    unsigned u = w[tid * 16 + i];
    unsigned e = (u >> 7) & 0xFF;
    c += (e >= 100 && e <= 140) ? 1 : 0;
  }
  cnt[tid] = c;
  __syncthreads();
  for (int s = 128; s > 0; s >>= 1) {
    if (tid < s) cnt[tid] += cnt[tid + s];
    __syncthreads();
  }
  if (tid == 0) *flag = (cnt[0] > 2048) ? 1 : 0;   // 1 = bf16 inputs
}

// ---------------- fused weight transposes: Wt[n][k] = bf16(W[k][n]) ----------------
template<typename T>
__device__ __forceinline__ void tr_body(const T* __restrict__ W, bf16* __restrict__ Wt,
                                        bf16 (*t)[33]) {
  int tx = threadIdx.x, ty = threadIdx.y;            // block (32,8)
  int x = blockIdx.x * 32 + tx;
  for (int r = 0; r < 4; r++)
    t[ty + r * 8][tx] = to_b(W[(blockIdx.y * 32 + ty + r * 8) * EE + x]);
  __syncthreads();
  int x2 = blockIdx.y * 32 + tx;
  for (int r = 0; r < 4; r++)
    Wt[(blockIdx.x * 32 + ty + r * 8) * EE + x2] = t[tx][ty + r * 8];
}

__global__ __launch_bounds__(256) void transpose_w4(
    const void* __restrict__ W0, const void* __restrict__ W1,
    const void* __restrict__ W2, const void* __restrict__ W3,
    bf16* __restrict__ T0, bf16* __restrict__ T1,
    bf16* __restrict__ T2, bf16* __restrict__ T3,
    const int* __restrict__ flag) {
  __shared__ bf16 t[32][33];
  int z = blockIdx.z;
  const void* W = (z == 0) ? W0 : (z == 1) ? W1 : (z == 2) ? W2 : W3;
  bf16* Wt      = (z == 0) ? T0 : (z == 1) ? T1 : (z == 2) ? T2 : T3;
  if (*flag) tr_body<bf16>((const bf16*)W, Wt, t);
  else       tr_body<float>((const float*)W, Wt, t);
}

// ---------------- 128x128 GEMM, BK=64, Bt is [N][K] bf16 ----------------
// XCD-aware remap (R6-verified): linear%8 = XCD; each XCD owns 8 contiguous
// m-panels (A slice L2-resident) x all n-tiles.
// A staged directly: bf16 -> async16; fp32 -> ld8 RNE convert + ds_write.
// mode 0: C bf16 row-major [M][E] + bias
// mode 2: C bf16 [B,H,D,L] + bias (v transposed head layout)
// mode 3: C TIO row-major [M][E] + bias (final output)
template<typename TA, typename TIO>
__device__ void gemm_body(const TA* __restrict__ A, const bf16* __restrict__ Bt,
                          const TIO* __restrict__ bias, void* __restrict__ Cv,
                          int mode, bf16* As, bf16* Bs) {
  constexpr int K = EE;
  int tid = threadIdx.x;
  int lane = tid & 63, w = tid >> 6;
  int l16 = lane & 15, quad = lane >> 4;
  int linear = blockIdx.x + 8 * blockIdx.y;      // grid (8,64[,z])
  int xcd = linear & 7;
  int slot = linear >> 3;
  int m0 = (xcd * 8 + (slot & 7)) * 128;         // m-tile
  int n0 = (slot >> 3) * 128;                    // n-tile
  int mw = (w & 1) * 64;
  int nw = (w >> 1) * 64;
  int lr = lane >> 3;            // staging row within 8-row group
  int lc = (lane & 7) * 8;       // staging col (elements), 64 elems/row

  f32x4 acc[4][4] = {};

  for (int k0 = 0; k0 < K; k0 += 64) {
    __syncthreads();
#pragma unroll
    for (int t = 0; t < 4; t++) {
      int R = w * 32 + t * 8;
      int r = R + lr;
      if constexpr (__is_same(TA, bf16)) {
        async16(A + (size_t)(m0 + r) * K + k0 + lc, As + R * 64);
      } else {
        *(bf16x8*)(As + r * 64 + lc) = ld8(A + (size_t)(m0 + r) * K + k0 + lc);
      }
      async16(Bt + (size_t)(n0 + r) * K + k0 + lc, Bs + R * 64);
    }
    __syncthreads();   // drains vmcnt+lgkmcnt before barrier (m97)
#pragma unroll
    for (int h = 0; h < 2; h++) {
      bf16x8 af[4], bfr[4];
#pragma unroll
      for (int t = 0; t < 4; t++) {
        af[t]  = *(const bf16x8*)(As + (mw + t * 16 + l16) * 64 + h * 32 + quad * 8);
        bfr[t] = *(const bf16x8*)(Bs + (nw + t * 16 + l16) * 64 + h * 32 + quad * 8);
      }
#pragma unroll
      for (int mt = 0; mt < 4; mt++)
#pragma unroll
        for (int nt = 0; nt < 4; nt++)
          acc[mt][nt] = __builtin_amdgcn_mfma_f32_16x16x32_bf16(af[mt], bfr[nt], acc[mt][nt], 0, 0, 0);
    }
  }

#pragma unroll
  for (int nt = 0; nt < 4; nt++) {
    int col = n0 + nw + nt * 16 + l16;
    float bv = ldf(bias + col);
    int hh = col >> 6, d = col & 63;
#pragma unroll
    for (int mt = 0; mt < 4; mt++) {
      f32x4 v = acc[mt][nt];
      int rowb = m0 + mw + mt * 16 + quad * 4;
      if (mode == 0) {
#pragma unroll
        for (int i = 0; i < 4; i++)
          ((bf16*)Cv)[(size_t)(rowb + i) * EE + col] = __float2bfloat16(v[i] + bv);
      } else if (mode == 3) {
#pragma unroll
        for (int i = 0; i < 4; i++) {
          float val = v[i] + bv;
          if constexpr (__is_same(TIO, bf16))
            ((bf16*)Cv)[(size_t)(rowb + i) * EE + col] = __float2bfloat16(val);
          else
            ((float*)Cv)[(size_t)(rowb + i) * EE + col] = val;
        }
      } else {  // mode 2: V^T [B,H,D,L], 4 consecutive l -> 8B store
        int b = rowb >> 11, l0 = rowb & 2047;
        union { s16x4 p; bf16 e[4]; } u;
#pragma unroll
        for (int i = 0; i < 4; i++) u.e[i] = __float2bfloat16(v[i] + bv);
        *(s16x4*)((bf16*)Cv + ((size_t)(b * HH + hh) * DD + d) * LL + l0) = u.p;
      }
    }
  }
}

__global__ __launch_bounds__(256) void qkv_gemm(
    const void* __restrict__ Q, const void* __restrict__ Kin, const void* __restrict__ V,
    const bf16* __restrict__ WQt, const bf16* __restrict__ WKt, const bf16* __restrict__ WVt,
    const void* __restrict__ bQ, const void* __restrict__ bK, const void* __restrict__ bV,
    bf16* __restrict__ qo, bf16* __restrict__ ko, bf16* __restrict__ vo,
    const int* __restrict__ flag) {
  __shared__ __align__(16) bf16 As[128 * 64];
  __shared__ __align__(16) bf16 Bs[128 * 64];
  int z = blockIdx.z;
  const void* A    = (z == 0) ? Q   : (z == 1) ? Kin : V;
  const bf16* Bt   = (z == 0) ? WQt : (z == 1) ? WKt : WVt;
  const void* bb   = (z == 0) ? bQ  : (z == 1) ? bK  : bV;
  bf16* C          = (z == 0) ? qo  : (z == 1) ? ko  : vo;
  int mode = (z == 2) ? 2 : 0;
  if (*flag) gemm_body<bf16, bf16>((const bf16*)A, Bt, (const bf16*)bb, C, mode, As, Bs);
  else       gemm_body<float, float>((const float*)A, Bt, (const float*)bb, C, mode, As, Bs);
}

__global__ __launch_bounds__(256) void out_gemm(const bf16* __restrict__ A,
                                                const bf16* __restrict__ WOt,
                                                const void* __restrict__ bO,
                                                void* __restrict__ C,
                                                const int* __restrict__ flag) {
  __shared__ __align__(16) bf16 As[128 * 64];
  __shared__ __align__(16) bf16 Bs[128 * 64];
  if (*flag) gemm_body<bf16, bf16>(A, WOt, (const bf16*)bO, C, 3, As, Bs);
  else       gemm_body<bf16, float>(A, WOt, (const float*)bO, C, 3, As, Bs);
}

// ---------------- flash attention, causal, S^T formulation, 128-q supertile ----------------
// q,k: [B,L,E] bf16   v: [B,H,D,L] bf16   out: [B,L,E] bf16
// grid (64 bh, 8 pairs): xcd = bh&7 -> 8 heads per XCD (K+V 4 MB = L2).
// Each block: one 128-q supertile (paired pr / 15-pr). Each wave: 32 q (2 groups of 16).
__global__ __launch_bounds__(256) void attn(const bf16* __restrict__ qg,
                                            const bf16* __restrict__ kg,
                                            const bf16* __restrict__ vg,
                                            bf16* __restrict__ outg) {
  __shared__ __align__(16) bf16 Ks[2][64 * 64];
  __shared__ __align__(16) bf16 Vs[2][64 * 64];
  int bh = blockIdx.x;               // head-batch 0..63; XCD = bh&7
  int pr = blockIdx.y;               // 0..7; handles supertiles pr and 15-pr
  int tid = threadIdx.x;
  int w = tid >> 6, lane = tid & 63, l16 = lane & 15, quad = lane >> 4;
  int b = bh >> 4, hh = bh & 15;

  const bf16* qp = qg + (size_t)b * LL * EE + hh * DD;
  const bf16* kp = kg + (size_t)b * LL * EE + hh * DD;
  const bf16* vp = vg + (size_t)bh * DD * LL;
  const f32x4 z4 = {};
  int x7 = l16 & 7;                  // read-side swizzle key (row&7 == l16&7, R6-verified)

  for (int half = 0; half < 2; half++) {
    int tile = half ? (15 - pr) : pr;
    int qrow0 = tile * 128 + w * 32;     // this wave's 32 q-rows (2 groups of 16)
    int qmax = qrow0 + 31;
    // Q B-frags for both groups
    bf16x8 bq[2][2];
#pragma unroll
    for (int g = 0; g < 2; g++) {
      const bf16* qr = qp + (size_t)(qrow0 + g * 16 + l16) * EE;
      bq[g][0] = *(const bf16x8*)(qr + quad * 8);
      bq[g][1] = *(const bf16x8*)(qr + 32 + quad * 8);
    }

    float m[2] = {-1.0e30f, -1.0e30f}, l[2] = {0.f, 0.f};
    f32x4 o[2][4] = {};
    int kend = 2 * (tile + 1);           // uniform across block

    __syncthreads();                     // protect buf0 from previous half's readers
    {                                    // prologue: stage kb=0 into buf 0
#pragma unroll
      for (int t = 0; t < 2; t++) {
        int R = w * 16 + t * 8;
        int r = R + (lane >> 3);
        int gb = (lane & 7) ^ (r & 7);
        async16(kp + (size_t)r * EE + gb * 8, &Ks[0][R * 64]);
        async16(vp + (size_t)r * LL + gb * 8, &Vs[0][R * 64]);
      }
    }

    for (int kb = 0; kb < kend; kb++) {
      int kbase = kb * 64;
      __syncthreads();                   // vmcnt drain: stage(kb) complete
      if (kb + 1 < kend) {               // prefetch next tile into other buffer
        int nb = (kb + 1) & 1;
        int nbase = kbase + 64;
#pragma unroll
        for (int t = 0; t < 2; t++) {
          int R = w * 16 + t * 8;
          int r = R + (lane >> 3);
          int gb = (lane & 7) ^ (r & 7);
          async16(kp + (size_t)(nbase + r) * EE + gb * 8, &Ks[nb][R * 64]);
          async16(vp + (size_t)r * LL + nbase + gb * 8, &Vs[nb][R * 64]);
        }
      }
      if (kbase > qmax) continue;        // fully masked for this wave (still did staging)
      const bf16* Kb = &Ks[kb & 1][0];
      const bf16* Vb = &Vs[kb & 1][0];

      // ---- S^T = K·Q^T for both groups; K-frags read once ----
      f32x4 s[2][4];
#pragma unroll
      for (int kt = 0; kt < 4; kt++) {
        int row = kt * 16 + l16;
        bf16x8 kf0 = *(const bf16x8*)(Kb + row * 64 + (quad ^ x7) * 8);
        bf16x8 kf1 = *(const bf16x8*)(Kb + row * 64 + ((quad + 4) ^ x7) * 8);
#pragma unroll
        for (int g = 0; g < 2; g++) {
          s[g][kt] = __builtin_amdgcn_mfma_f32_16x16x32_bf16(kf0, bq[g][0], z4, 0, 0, 0);
          s[g][kt] = __builtin_amdgcn_mfma_f32_16x16x32_bf16(kf1, bq[g][1], s[g][kt], 0, 0, 0);
        }
      }
#if __has_builtin(__builtin_amdgcn_mfma_f32_16x16x16bf16_1k)
      s16x4 vf[4][4];   // V^T A-frags: A[m=d=l16][k=key=quad*4+j], shared by groups
#pragma unroll
      for (int j = 0; j < 4; j++)
#pragma unroll
        for (int kt = 0; kt < 4; kt++)
          vf[j][kt] = *(const s16x4*)(Vb + (j * 16 + l16) * 64 +
                                      ((kt * 2 + (quad >> 1)) ^ x7) * 8 + (quad & 1) * 4);
#endif
      union { s16x4 v4; bf16 e[4]; unsigned u[2]; } pk[2][4];
#pragma unroll
      for (int g = 0; g < 2; g++) {
        int qg_ = qrow0 + g * 16 + l16;
        float sv[16];
        if (kbase + 63 <= qrow0 + g * 16) {
#pragma unroll
          for (int kt = 0; kt < 4; kt++)
#pragma unroll
            for (int i = 0; i < 4; i++) sv[kt * 4 + i] = s[g][kt][i] * SCL;
        } else {
          int rel = qg_ - kbase - quad * 4;
#pragma unroll
          for (int kt = 0; kt < 4; kt++)
#pragma unroll
            for (int i = 0; i < 4; i++)
              sv[kt * 4 + i] = (kt * 16 + i <= rel) ? s[g][kt][i] * SCL : -1.0e30f;
        }
        float mloc = sv[0];
#pragma unroll
        for (int i = 1; i < 16; i++) mloc = fmaxf(mloc, sv[i]);
        mloc = fmaxf(mloc, __shfl_xor(mloc, 16));
        mloc = fmaxf(mloc, __shfl_xor(mloc, 32));
        float mnew = fmaxf(m[g], mloc);
        float alpha = exp2f((m[g] - mnew) * L2E);
        float p[16], ssum = 0.f;
#pragma unroll
        for (int i = 0; i < 16; i++) { p[i] = exp2f((sv[i] - mnew) * L2E); ssum += p[i]; }
        ssum += __shfl_xor(ssum, 16);
        ssum += __shfl_xor(ssum, 32);
        l[g] = l[g] * alpha + ssum;
        m[g] = mnew;
#pragma unroll
        for (int j = 0; j < 4; j++)
#pragma unroll
          for (int i = 0; i < 4; i++) o[g][j][i] *= alpha;
#pragma unroll
        for (int kt = 0; kt < 4; kt++)
#pragma unroll
          for (int i = 0; i < 4; i++) pk[g][kt].e[i] = __float2bfloat16(p[kt * 4 + i]);
      }
#if __has_builtin(__builtin_amdgcn_mfma_f32_16x16x16bf16_1k)
#pragma unroll
      for (int kt = 0; kt < 4; kt++)
#pragma unroll
        for (int j = 0; j < 4; j++) {
          o[0][j] = __builtin_amdgcn_mfma_f32_16x16x16bf16_1k(vf[j][kt], pk[0][kt].v4, o[0][j], 0, 0, 0);
          o[1][j] = __builtin_amdgcn_mfma_f32_16x16x16bf16_1k(vf[j][kt], pk[1][kt].v4, o[1][j], 0, 0, 0);
        }
#else
#pragma unroll
      for (int g = 0; g < 2; g++)
#pragma unroll
        for (int c = 0; c < 2; c++) {
          union { bf16x8 v8; unsigned u[4]; } bfr;
#pragma unroll
          for (int r = 0; r < 4; r++) {
            int key = c * 32 + quad * 8 + 2 * r;
            int srcl = (((key >> 2) & 3) << 4) + l16;
            unsigned v0 = __shfl((int)pk[g][2 * c].u[r & 1], srcl, 64);
            unsigned v1 = __shfl((int)pk[g][2 * c + 1].u[r & 1], srcl, 64);
            bfr.u[r] = (quad < 2) ? v0 : v1;
          }
#pragma unroll
          for (int j = 0; j < 4; j++) {
            bf16x8 vfr = *(const bf16x8*)(Vb + (j * 16 + l16) * 64 + ((c * 4 + quad) ^ x7) * 8);
            o[g][j] = __builtin_amdgcn_mfma_f32_16x16x32_bf16(vfr, bfr.v8, o[g][j], 0, 0, 0);
          }
        }
#endif
    }
    // ---- epilogue: O^T frag (d = j*16+quad*4+i, q = l16), 8B packed stores ----
#pragma unroll
    for (int g = 0; g < 2; g++) {
      float inv = 1.0f / l[g];
      int qg_ = qrow0 + g * 16 + l16;
#pragma unroll
      for (int j = 0; j < 4; j++) {
        union { s16x4 v4; bf16 e[4]; } u;
#pragma unroll
        for (int i = 0; i < 4; i++) u.e[i] = __float2bfloat16(o[g][j][i] * inv);
        *(s16x4*)(outg + (size_t)(b * LL + qg_) * EE + hh * DD + j * 16 + quad * 4) = u.v4;
      }
    }
  }
}

extern "C" void kernel_launch(void* const* d_in, const int* in_sizes, int n_in,
                              void* d_out, int out_size, void* d_ws, size_t ws_size,
                              hipStream_t stream) {
  const void* Q   = d_in[0];
  const void* Kin = d_in[1];
  const void* V   = d_in[2];
  const void* WQ  = d_in[3];
  const void* bQ  = d_in[4];
  const void* WK  = d_in[5];
  const void* bK  = d_in[6];
  const void* WV  = d_in[7];
  const void* bV  = d_in[8];
  const void* WO  = d_in[9];
  const void* bO  = d_in[10];

  int* flag = (int*)d_ws;
  bf16* base = (bf16*)((char*)d_ws + 256);
  bf16* wqt  = base;                        // 4 x 1024^2 bf16
  bf16* wkt  = wqt + (size_t)EE * EE;
  bf16* wvt  = wkt + (size_t)EE * EE;
  bf16* wot  = wvt + (size_t)EE * EE;
  bf16* qws  = wot + (size_t)EE * EE;       // projected q  [B,L,E]
  bf16* kws  = qws + (size_t)MM * EE;       // projected k  [B,L,E]
  bf16* vws  = kws + (size_t)MM * EE;       // projected v  [B,H,D,L]
  bf16* aout = vws + (size_t)MM * EE;       // attention out [B,L,E]

  detect_dtype<<<1, 256, 0, stream>>>((const unsigned int*)WQ, flag);

  transpose_w4<<<dim3(32, 32, 4), dim3(32, 8), 0, stream>>>(
      WQ, WK, WV, WO, wqt, wkt, wvt, wot, flag);

  qkv_gemm<<<dim3(8, 64, 3), 256, 0, stream>>>(
      Q, Kin, V, wqt, wkt, wvt, bQ, bK, bV, qws, kws, vws, flag);

  attn<<<dim3(64, 8), 256, 0, stream>>>(qws, kws, vws, aout);

  out_gemm<<<dim3(8, 64), 256, 0, stream>>>(aout, wot, bO, d_out, flag);
}